// Round 1
// 646.080 us; speedup vs baseline: 1.0426x; 1.0426x over previous
//
#include <hip/hip_runtime.h>
#include <hip/hip_bf16.h>

#define E_EDGES 800000
#define NN 50000
#define BN_EPS 1e-5f

typedef __bf16 bf16x8 __attribute__((ext_vector_type(8)));
typedef __bf16 bf16x4 __attribute__((ext_vector_type(4)));
typedef float f32x4 __attribute__((ext_vector_type(4)));

// ---------------------------------------------------------------------------
// Prep: transpose + bf16-convert weights. Wt[n][k] = W[k][n].
// ---------------------------------------------------------------------------
__global__ void k_prep(const float* __restrict__ W0, const float* __restrict__ W1,
                       const float* __restrict__ W2, __bf16* __restrict__ W0t_top,
                       __bf16* __restrict__ W0t_bot, __bf16* __restrict__ Wt1,
                       __bf16* __restrict__ Wt2)
{
    for (int i = threadIdx.x; i < 4096; i += 256) {
        const int n = i >> 6, k = i & 63;
        W0t_top[n * 64 + k] = (__bf16)W0[k * 64 + n];
        W0t_bot[n * 64 + k] = (__bf16)W0[(64 + k) * 64 + n];
        Wt1[n * 64 + k] = (__bf16)W1[k * 64 + n];
        Wt2[n * 64 + k] = (__bf16)W2[k * 64 + n];
    }
}

// ---------------------------------------------------------------------------
// dst-degree histogram (int atomics, ~16 per address).
// ---------------------------------------------------------------------------
__global__ __launch_bounds__(256) void k_count(
    const int* __restrict__ ei, int* __restrict__ counts)
{
    const int e = blockIdx.x * 256 + threadIdx.x;
    atomicAdd(&counts[ei[E_EDGES + e]], 1);
}

// ---------------------------------------------------------------------------
// Exclusive scan of counts[NN] -> offsets, cursor.
// ---------------------------------------------------------------------------
__global__ __launch_bounds__(256) void k_scan(
    const int* __restrict__ counts, int* __restrict__ offsets,
    int* __restrict__ cursor)
{
    const int CHUNK = (NN + 255) / 256;  // 196
    const int t = threadIdx.x;
    const int beg = t * CHUNK;
    const int end = (beg + CHUNK < NN) ? beg + CHUNK : NN;
    int mysum = 0;
    for (int i = beg; i < end; ++i) mysum += counts[i];

    __shared__ int sd[256];
    sd[t] = mysum;
    __syncthreads();
    int run = mysum;
    for (int off = 1; off < 256; off <<= 1) {
        int v = (t >= off) ? sd[t - off] : 0;
        __syncthreads();
        sd[t] += v;
        __syncthreads();
    }
    int prefix = sd[t] - run;
    for (int i = beg; i < end; ++i) {
        offsets[i] = prefix;
        cursor[i] = prefix;
        prefix += counts[i];
    }
}

// ---------------------------------------------------------------------------
// Node GEMM (swapped operands): P = x @ W0_top, Q = x @ W0_bot (bf16 out).
// ---------------------------------------------------------------------------
__global__ __launch_bounds__(256) void k_gemm_node(
    const float* __restrict__ x, const __bf16* __restrict__ W0t_top,
    const __bf16* __restrict__ W0t_bot, __bf16* __restrict__ P,
    __bf16* __restrict__ Q)
{
    const int wave = threadIdx.x >> 6;
    const int grp = blockIdx.x * 4 + wave;
    if (grp >= NN / 16) return;  // 3125 groups
    const int lane = threadIdx.x & 63;
    const int quad = lane >> 4, lr = lane & 15;

    bf16x8 aT[4][2], aB[4][2];
#pragma unroll
    for (int mt = 0; mt < 4; ++mt)
#pragma unroll
        for (int s = 0; s < 2; ++s) {
            const int off = (mt * 16 + lr) * 64 + s * 32 + quad * 8;
            aT[mt][s] = *(const bf16x8*)(W0t_top + off);
            aB[mt][s] = *(const bf16x8*)(W0t_bot + off);
        }

    const int node = grp * 16 + lr;
    bf16x8 bx[2];
#pragma unroll
    for (int s = 0; s < 2; ++s) {
        const float4* ap = (const float4*)(x + (size_t)node * 64 + s * 32 + quad * 8);
        const float4 v0 = ap[0], v1 = ap[1];
        bx[s][0] = (__bf16)v0.x; bx[s][1] = (__bf16)v0.y;
        bx[s][2] = (__bf16)v0.z; bx[s][3] = (__bf16)v0.w;
        bx[s][4] = (__bf16)v1.x; bx[s][5] = (__bf16)v1.y;
        bx[s][6] = (__bf16)v1.z; bx[s][7] = (__bf16)v1.w;
    }

    f32x4 accP[4], accQ[4];
#pragma unroll
    for (int mt = 0; mt < 4; ++mt) {
        accP[mt] = (f32x4){0.f, 0.f, 0.f, 0.f};
        accQ[mt] = (f32x4){0.f, 0.f, 0.f, 0.f};
    }
#pragma unroll
    for (int s = 0; s < 2; ++s)
#pragma unroll
        for (int mt = 0; mt < 4; ++mt) {
            accP[mt] = __builtin_amdgcn_mfma_f32_16x16x32_bf16(aT[mt][s], bx[s], accP[mt], 0, 0, 0);
            accQ[mt] = __builtin_amdgcn_mfma_f32_16x16x32_bf16(aB[mt][s], bx[s], accQ[mt], 0, 0, 0);
        }

#pragma unroll
    for (int mt = 0; mt < 4; ++mt) {
        bf16x4 pv, qv;
#pragma unroll
        for (int r = 0; r < 4; ++r) { pv[r] = (__bf16)accP[mt][r]; qv[r] = (__bf16)accQ[mt][r]; }
        const size_t o = (size_t)node * 64 + mt * 16 + quad * 4;
        *(bf16x4*)(P + o) = pv;
        *(bf16x4*)(Q + o) = qv;
    }
}

// ---------------------------------------------------------------------------
// Fused CSR fill + BN0 stats. 2 threads per edge (32 cols each), grid-stride.
// Thread pair: half0 does the cursor atomic, writes ONE packed int4 record
// {eidx, src, dst, 0} (single 16B scatter instead of 3x4B), both halves
// gather P[dst]/Q[src] rows (L2/L3-resident) and accumulate per-column
// sum/sumsq of v = P[dst]+Q[src]. t0 is NEVER materialized.
// ---------------------------------------------------------------------------
__global__ __launch_bounds__(256) void k_fill_stats(
    const int* __restrict__ ei, int* __restrict__ cursor,
    const __bf16* __restrict__ P, const __bf16* __restrict__ Q,
    int4* __restrict__ rec, float* __restrict__ sums)
{
    float sa[32], sq[32];
#pragma unroll
    for (int j = 0; j < 32; ++j) { sa[j] = 0.f; sq[j] = 0.f; }

    const int lane = threadIdx.x & 63;
    const int stride = gridDim.x * 256;
    for (int s = blockIdx.x * 256 + threadIdx.x; s < 2 * E_EDGES; s += stride) {
        const int e = s >> 1, half = s & 1;
        const int src = ei[e];
        const int dst = ei[E_EDGES + e];
        int pos = 0;
        if (half == 0) pos = atomicAdd(&cursor[dst], 1);
        pos = __shfl(pos, lane & ~1);

        const bf16x8* pp = (const bf16x8*)(P + (size_t)dst * 64 + half * 32);
        const bf16x8* qp = (const bf16x8*)(Q + (size_t)src * 64 + half * 32);
        bf16x8 pf0 = pp[0], pf1 = pp[1], pf2 = pp[2], pf3 = pp[3];
        bf16x8 qf0 = qp[0], qf1 = qp[1], qf2 = qp[2], qf3 = qp[3];

        if (half == 0) rec[pos] = make_int4(e, src, dst, 0);

        float v[32];
#pragma unroll
        for (int j = 0; j < 8; ++j) {
            v[j]      = (float)pf0[j] + (float)qf0[j];
            v[8 + j]  = (float)pf1[j] + (float)qf1[j];
            v[16 + j] = (float)pf2[j] + (float)qf2[j];
            v[24 + j] = (float)pf3[j] + (float)qf3[j];
        }
#pragma unroll
        for (int j = 0; j < 32; ++j) { sa[j] += v[j]; sq[j] = fmaf(v[j], v[j], sq[j]); }
    }

#pragma unroll
    for (int off = 2; off < 64; off <<= 1)
#pragma unroll
        for (int j = 0; j < 32; ++j) {
            sa[j] += __shfl_xor(sa[j], off);
            sq[j] += __shfl_xor(sq[j], off);
        }

    __shared__ float red[4][128];
    const int wave = threadIdx.x >> 6;
    if (lane < 2) {
        const int cbase = lane * 32;
#pragma unroll
        for (int j = 0; j < 32; ++j) {
            red[wave][cbase + j] = sa[j];
            red[wave][64 + cbase + j] = sq[j];
        }
    }
    __syncthreads();
    if (threadIdx.x < 128) {
        float v2 = red[0][threadIdx.x] + red[1][threadIdx.x] + red[2][threadIdx.x] + red[3][threadIdx.x];
        atomicAdd(&sums[threadIdx.x], v2);
    }
}

// ---------------------------------------------------------------------------
// Layer-1 GEMM: recomputes t0 rows on the fly via P[dst]+Q[src] gathers
// (dst is CSR-sorted -> P rows cache-hot), applies BN0 affine+relu in fp32,
// MFMA with W1, writes t (bf16, CSR order), fused stats1 epilogue.
// 1250 blocks x 4 waves, 10 groups/wave, rec/gather prefetch pipeline.
// ---------------------------------------------------------------------------
__global__ __launch_bounds__(256) void k_gemm_mid1(
    const __bf16* __restrict__ P, const __bf16* __restrict__ Q,
    const int4* __restrict__ rec, __bf16* __restrict__ tout,
    const __bf16* __restrict__ Wt, const float* __restrict__ sums_in,
    const float* __restrict__ g, const float* __restrict__ beta,
    float* __restrict__ sums_out)
{
    __shared__ float clds[128];
    __shared__ float sred[4][64], qred[4][64];
    if (threadIdx.x < 64) {
        const float inv_e = 1.f / (float)E_EDGES;
        const float mu = sums_in[threadIdx.x] * inv_e;
        const float var = sums_in[64 + threadIdx.x] * inv_e - mu * mu;
        const float a = g[threadIdx.x] * rsqrtf(var + BN_EPS);
        clds[threadIdx.x] = a;
        clds[64 + threadIdx.x] = beta[threadIdx.x] - mu * a;
    }
    __syncthreads();

    const int wave = threadIdx.x >> 6;
    const int lane = threadIdx.x & 63;
    const int quad = lane >> 4, lr = lane & 15;

    float ar[2][8], cr[2][8];
#pragma unroll
    for (int s = 0; s < 2; ++s)
#pragma unroll
        for (int j = 0; j < 8; ++j) {
            const int k = s * 32 + quad * 8 + j;
            ar[s][j] = clds[k];
            cr[s][j] = clds[64 + k];
        }

    bf16x8 af[4][2];
#pragma unroll
    for (int mt = 0; mt < 4; ++mt)
#pragma unroll
        for (int s = 0; s < 2; ++s)
            af[mt][s] = *(const bf16x8*)(Wt + (mt * 16 + lr) * 64 + s * 32 + quad * 8);

    float ss[16], sq[16];
#pragma unroll
    for (int i = 0; i < 16; ++i) { ss[i] = 0.f; sq[i] = 0.f; }

    const int WAVES = 1250 * 4;
    int grp = blockIdx.x * 4 + wave;      // 10 iterations exactly
    size_t ebase = (size_t)(grp * 16 + lr) * 64;

    // pipeline: rec 2 iterations ahead, gathers 1 iteration ahead
    int4 rc = rec[grp * 16 + lr];
    bf16x8 pcur0 = *(const bf16x8*)(P + (size_t)rc.z * 64 + quad * 8);
    bf16x8 pcur1 = *(const bf16x8*)(P + (size_t)rc.z * 64 + 32 + quad * 8);
    bf16x8 qcur0 = *(const bf16x8*)(Q + (size_t)rc.y * 64 + quad * 8);
    bf16x8 qcur1 = *(const bf16x8*)(Q + (size_t)rc.y * 64 + 32 + quad * 8);
    int4 rn = rec[(grp + WAVES) * 16 + lr];  // grp+WAVES < 50000 for it<9 path

#pragma unroll 1
    for (int it = 0; it < 10; ++it) {
        bf16x8 pn0, pn1, qn0, qn1;
        int4 rn2 = rn;
        if (it < 9) {
            pn0 = *(const bf16x8*)(P + (size_t)rn.z * 64 + quad * 8);
            pn1 = *(const bf16x8*)(P + (size_t)rn.z * 64 + 32 + quad * 8);
            qn0 = *(const bf16x8*)(Q + (size_t)rn.y * 64 + quad * 8);
            qn1 = *(const bf16x8*)(Q + (size_t)rn.y * 64 + 32 + quad * 8);
        }
        if (it < 8) rn2 = rec[(grp + 2 * WAVES) * 16 + lr];

        bf16x8 bact0, bact1;
#pragma unroll
        for (int j = 0; j < 8; ++j) {
            const float v0 = (float)pcur0[j] + (float)qcur0[j];
            const float v1 = (float)pcur1[j] + (float)qcur1[j];
            bact0[j] = (__bf16)fmaxf(fmaf(v0, ar[0][j], cr[0][j]), 0.f);
            bact1[j] = (__bf16)fmaxf(fmaf(v1, ar[1][j], cr[1][j]), 0.f);
        }

        f32x4 acc[4];
#pragma unroll
        for (int mt = 0; mt < 4; ++mt) acc[mt] = (f32x4){0.f, 0.f, 0.f, 0.f};
#pragma unroll
        for (int mt = 0; mt < 4; ++mt) {
            acc[mt] = __builtin_amdgcn_mfma_f32_16x16x32_bf16(af[mt][0], bact0, acc[mt], 0, 0, 0);
            acc[mt] = __builtin_amdgcn_mfma_f32_16x16x32_bf16(af[mt][1], bact1, acc[mt], 0, 0, 0);
        }

#pragma unroll
        for (int mt = 0; mt < 4; ++mt) {
            bf16x4 pv;
#pragma unroll
            for (int r = 0; r < 4; ++r) pv[r] = (__bf16)acc[mt][r];
            *(bf16x4*)(tout + ebase + mt * 16 + quad * 4) = pv;
#pragma unroll
            for (int r = 0; r < 4; ++r) {
                const float v = acc[mt][r];
                ss[mt * 4 + r] += v;
                sq[mt * 4 + r] = fmaf(v, v, sq[mt * 4 + r]);
            }
        }

        pcur0 = pn0; pcur1 = pn1; qcur0 = qn0; qcur1 = qn1;
        rn = rn2;
        grp += WAVES;
        ebase = (size_t)(grp * 16 + lr) * 64;
    }

#pragma unroll
    for (int i = 0; i < 16; ++i) {
        ss[i] += __shfl_xor(ss[i], 1); ss[i] += __shfl_xor(ss[i], 2);
        ss[i] += __shfl_xor(ss[i], 4); ss[i] += __shfl_xor(ss[i], 8);
        sq[i] += __shfl_xor(sq[i], 1); sq[i] += __shfl_xor(sq[i], 2);
        sq[i] += __shfl_xor(sq[i], 4); sq[i] += __shfl_xor(sq[i], 8);
    }
    if (lr == 0) {
#pragma unroll
        for (int mt = 0; mt < 4; ++mt)
#pragma unroll
            for (int r = 0; r < 4; ++r) {
                sred[wave][mt * 16 + quad * 4 + r] = ss[mt * 4 + r];
                qred[wave][mt * 16 + quad * 4 + r] = sq[mt * 4 + r];
            }
    }
    __syncthreads();
    if (threadIdx.x < 64) {
        const int c = threadIdx.x;
        atomicAdd(&sums_out[c], sred[0][c] + sred[1][c] + sred[2][c] + sred[3][c]);
        atomicAdd(&sums_out[64 + c], qred[0][c] + qred[1][c] + qred[2][c] + qred[3][c]);
    }
}

// ---------------------------------------------------------------------------
// Layer-2 GEMM (streaming): bf16 in -> bf16 out in place; prev-BN
// affine+relu on load; fused stats epilogue. 1250 blocks x 4 waves.
// ---------------------------------------------------------------------------
__global__ __launch_bounds__(256) void k_gemm_mid(
    const __bf16* __restrict__ tin, __bf16* __restrict__ tout,
    const __bf16* __restrict__ Wt, const float* __restrict__ sums_in,
    const float* __restrict__ g, const float* __restrict__ beta,
    float* __restrict__ sums_out)
{
    __shared__ float clds[128];
    __shared__ float sred[4][64], qred[4][64];
    if (threadIdx.x < 64) {
        const float inv_e = 1.f / (float)E_EDGES;
        const float mu = sums_in[threadIdx.x] * inv_e;
        const float var = sums_in[64 + threadIdx.x] * inv_e - mu * mu;
        const float a = g[threadIdx.x] * rsqrtf(var + BN_EPS);
        clds[threadIdx.x] = a;
        clds[64 + threadIdx.x] = beta[threadIdx.x] - mu * a;
    }
    __syncthreads();

    const int wave = threadIdx.x >> 6;
    const int lane = threadIdx.x & 63;
    const int quad = lane >> 4, lr = lane & 15;

    float ar[2][8], cr[2][8];
#pragma unroll
    for (int s = 0; s < 2; ++s)
#pragma unroll
        for (int j = 0; j < 8; ++j) {
            const int k = s * 32 + quad * 8 + j;
            ar[s][j] = clds[k];
            cr[s][j] = clds[64 + k];
        }

    bf16x8 af[4][2];
#pragma unroll
    for (int mt = 0; mt < 4; ++mt)
#pragma unroll
        for (int s = 0; s < 2; ++s)
            af[mt][s] = *(const bf16x8*)(Wt + (mt * 16 + lr) * 64 + s * 32 + quad * 8);

    float ss[16], sq[16];
#pragma unroll
    for (int i = 0; i < 16; ++i) { ss[i] = 0.f; sq[i] = 0.f; }

    const int WAVES = 1250 * 4;
    int grp = blockIdx.x * 4 + wave;      // 10 iterations exactly
    size_t ebase = (size_t)(grp * 16 + lr) * 64;

    bf16x8 bcur0 = *(const bf16x8*)(tin + ebase + quad * 8);
    bf16x8 bcur1 = *(const bf16x8*)(tin + ebase + 32 + quad * 8);

#pragma unroll 1
    for (int it = 0; it < 10; ++it) {
        const int gn = grp + WAVES;
        const size_t enext = (size_t)(gn * 16 + lr) * 64;
        bf16x8 bn0, bn1;
        if (it < 9) {
            bn0 = *(const bf16x8*)(tin + enext + quad * 8);
            bn1 = *(const bf16x8*)(tin + enext + 32 + quad * 8);
        }

        bf16x8 bact0, bact1;
#pragma unroll
        for (int j = 0; j < 8; ++j) {
            bact0[j] = (__bf16)fmaxf(fmaf((float)bcur0[j], ar[0][j], cr[0][j]), 0.f);
            bact1[j] = (__bf16)fmaxf(fmaf((float)bcur1[j], ar[1][j], cr[1][j]), 0.f);
        }

        f32x4 acc[4];
#pragma unroll
        for (int mt = 0; mt < 4; ++mt) acc[mt] = (f32x4){0.f, 0.f, 0.f, 0.f};
#pragma unroll
        for (int mt = 0; mt < 4; ++mt) {
            acc[mt] = __builtin_amdgcn_mfma_f32_16x16x32_bf16(af[mt][0], bact0, acc[mt], 0, 0, 0);
            acc[mt] = __builtin_amdgcn_mfma_f32_16x16x32_bf16(af[mt][1], bact1, acc[mt], 0, 0, 0);
        }

#pragma unroll
        for (int mt = 0; mt < 4; ++mt) {
            bf16x4 pv;
#pragma unroll
            for (int r = 0; r < 4; ++r) pv[r] = (__bf16)acc[mt][r];
            *(bf16x4*)(tout + ebase + mt * 16 + quad * 4) = pv;
#pragma unroll
            for (int r = 0; r < 4; ++r) {
                const float v = acc[mt][r];
                ss[mt * 4 + r] += v;
                sq[mt * 4 + r] = fmaf(v, v, sq[mt * 4 + r]);
            }
        }

        bcur0 = bn0; bcur1 = bn1;
        grp = gn; ebase = enext;
    }

#pragma unroll
    for (int i = 0; i < 16; ++i) {
        ss[i] += __shfl_xor(ss[i], 1); ss[i] += __shfl_xor(ss[i], 2);
        ss[i] += __shfl_xor(ss[i], 4); ss[i] += __shfl_xor(ss[i], 8);
        sq[i] += __shfl_xor(sq[i], 1); sq[i] += __shfl_xor(sq[i], 2);
        sq[i] += __shfl_xor(sq[i], 4); sq[i] += __shfl_xor(sq[i], 8);
    }
    if (lr == 0) {
#pragma unroll
        for (int mt = 0; mt < 4; ++mt)
#pragma unroll
            for (int r = 0; r < 4; ++r) {
                sred[wave][mt * 16 + quad * 4 + r] = ss[mt * 4 + r];
                qred[wave][mt * 16 + quad * 4 + r] = sq[mt * 4 + r];
            }
    }
    __syncthreads();
    if (threadIdx.x < 64) {
        const int c = threadIdx.x;
        atomicAdd(&sums_out[c], sred[0][c] + sred[1][c] + sred[2][c] + sred[3][c]);
        atomicAdd(&sums_out[64 + c], qred[0][c] + qred[1][c] + qred[2][c] + qred[3][c]);
    }
}

// ---------------------------------------------------------------------------
// Final: per node (one wave), node's rows are CONTIGUOUS in tb (CSR order).
// 8 rows x 8 lanes per step: lane reads 16B bf16 (coalesced 1KB/wave),
// applies BN2+relu, scatter-writes the fp32 edge_activations row to its
// original edge slot (full-line writes), reduces, writes mean.
// ---------------------------------------------------------------------------
__global__ __launch_bounds__(256) void k_gather_apply(
    const __bf16* __restrict__ tb, const int* __restrict__ offsets,
    const int* __restrict__ counts, const int4* __restrict__ rec,
    const float* __restrict__ sums_in, const float* __restrict__ g,
    const float* __restrict__ beta, float* __restrict__ tea,
    float* __restrict__ out)
{
    __shared__ float clds[128];
    if (threadIdx.x < 64) {
        const float inv_e = 1.f / (float)E_EDGES;
        const float mu = sums_in[threadIdx.x] * inv_e;
        const float var = sums_in[64 + threadIdx.x] * inv_e - mu * mu;
        const float a = g[threadIdx.x] * rsqrtf(var + BN_EPS);
        clds[threadIdx.x] = a;
        clds[64 + threadIdx.x] = beta[threadIdx.x] - mu * a;
    }
    __syncthreads();

    const int node = blockIdx.x * 4 + (threadIdx.x >> 6);
    const int lane = threadIdx.x & 63;
    const int es = lane >> 3;  // row slot 0..7
    const int cc = lane & 7;   // col chunk (8 cols)

    float a[8], c[8];
#pragma unroll
    for (int j = 0; j < 8; ++j) { a[j] = clds[cc * 8 + j]; c[j] = clds[64 + cc * 8 + j]; }

    const int beg = offsets[node];
    const int cnt = counts[node];

    float acc8[8];
#pragma unroll
    for (int j = 0; j < 8; ++j) acc8[j] = 0.f;

    for (int i = 0; i < cnt; i += 8) {
        const int sub = i + es;
        if (sub < cnt) {
            const int p = beg + sub;
            const bf16x8 v = *(const bf16x8*)(tb + (size_t)p * 64 + cc * 8);
            const int e = rec[p].x;
            float vv[8];
#pragma unroll
            for (int j = 0; j < 8; ++j)
                vv[j] = fmaxf(fmaf((float)v[j], a[j], c[j]), 0.f);
            float* rp = tea + (size_t)e * 64 + cc * 8;
            *(float4*)rp = make_float4(vv[0], vv[1], vv[2], vv[3]);
            *(float4*)(rp + 4) = make_float4(vv[4], vv[5], vv[6], vv[7]);
#pragma unroll
            for (int j = 0; j < 8; ++j) acc8[j] += vv[j];
        }
    }

#pragma unroll
    for (int j = 0; j < 8; ++j) {
        acc8[j] += __shfl_xor(acc8[j], 8);
        acc8[j] += __shfl_xor(acc8[j], 16);
        acc8[j] += __shfl_xor(acc8[j], 32);
    }
    if (lane < 8) {  // es==0, cc==lane
        const float inv = 1.f / fmaxf((float)cnt, 1.f);
        float* op = out + (size_t)node * 64 + lane * 8;
        *(float4*)op = make_float4(acc8[0] * inv, acc8[1] * inv, acc8[2] * inv, acc8[3] * inv);
        *(float4*)(op + 4) = make_float4(acc8[4] * inv, acc8[5] * inv, acc8[6] * inv, acc8[7] * inv);
    }
}

extern "C" void kernel_launch(void* const* d_in, const int* in_sizes, int n_in,
                              void* d_out, int out_size, void* d_ws, size_t ws_size,
                              hipStream_t stream)
{
    (void)in_sizes; (void)n_in; (void)out_size; (void)ws_size;

    const float* x     = (const float*)d_in[0];
    const int*   ei    = (const int*)d_in[1];
    const float* W0    = (const float*)d_in[2];
    const float* g0    = (const float*)d_in[4];
    const float* beta0 = (const float*)d_in[5];
    const float* W1    = (const float*)d_in[6];
    const float* g1    = (const float*)d_in[8];
    const float* beta1 = (const float*)d_in[9];
    const float* W2    = (const float*)d_in[10];
    const float* g2    = (const float*)d_in[12];
    const float* beta2 = (const float*)d_in[13];

    float* out = (float*)d_out;            // [NN*64] node output
    float* tea = out + (size_t)NN * 64;    // [E*64] fp32 edge_activations

    char* ws = (char*)d_ws;
    int*    counts  = (int*)(ws + 0);             // 200000 B
    int*    offsets = (int*)(ws + 200704);
    int*    cursor  = (int*)(ws + 401408);
    float*  sums0   = (float*)(ws + 602112);      // 512 B each, contiguous
    float*  sums1   = (float*)(ws + 602624);
    float*  sums2   = (float*)(ws + 603136);
    __bf16* W0t_top = (__bf16*)(ws + 603648);     // 8192 B each
    __bf16* W0t_bot = (__bf16*)(ws + 611840);
    __bf16* Wt1     = (__bf16*)(ws + 620032);
    __bf16* Wt2     = (__bf16*)(ws + 628224);
    __bf16* P       = (__bf16*)(ws + 636928);     // 6.4 MB
    __bf16* Q       = (__bf16*)(ws + 7036928);    // 6.4 MB
    int4*   rec     = (int4*)(ws + 13436928);     // 12.8 MB packed {e,src,dst,0}
    __bf16* tb      = (__bf16*)(ws + 26236928);   // 102.4 MB bf16 t (CSR order)

    hipMemsetAsync(counts, 0, NN * sizeof(int), stream);
    hipMemsetAsync(sums0, 0, 3 * 512, stream);

    const int GB = E_EDGES / 256;  // 3125

    k_prep<<<1, 256, 0, stream>>>(W0, W1, W2, W0t_top, W0t_bot, Wt1, Wt2);
    k_count<<<GB, 256, 0, stream>>>(ei, counts);
    k_scan<<<1, 256, 0, stream>>>(counts, offsets, cursor);
    k_gemm_node<<<782, 256, 0, stream>>>(x, W0t_top, W0t_bot, P, Q);

    // Fused CSR fill + BN0 stats (t0 never materialized).
    k_fill_stats<<<1563, 256, 0, stream>>>(ei, cursor, P, Q, rec, sums0);

    // Layer1: gather P[dst]+Q[src] on the fly; Layer2: streaming in-place.
    k_gemm_mid1<<<1250, 256, 0, stream>>>(P, Q, rec, tb, Wt1, sums0, g0, beta0, sums1);
    k_gemm_mid<<<1250, 256, 0, stream>>>(tb, tb, Wt2, sums1, g1, beta1, sums2);

    k_gather_apply<<<NN / 4, 256, 0, stream>>>(tb, offsets, counts, rec,
                                               sums2, g2, beta2, tea, out);
}

// Round 2
// 533.507 us; speedup vs baseline: 1.2627x; 1.2110x over previous
//
#include <hip/hip_runtime.h>
#include <hip/hip_bf16.h>

#define E_EDGES 800000
#define NN 50000
#define BN_EPS 1e-5f

typedef __bf16 bf16x8 __attribute__((ext_vector_type(8)));
typedef __bf16 bf16x4 __attribute__((ext_vector_type(4)));
typedef float f32x4 __attribute__((ext_vector_type(4)));

// ---------------------------------------------------------------------------
// Prep + zero: 196 blocks. Every block zeroes a slice of counts; block 0 also
// transposes+bf16-converts the weights and zeroes the sums (replaces 2
// hipMemsetAsync + 1-block k_prep = 3 dispatches).
// ---------------------------------------------------------------------------
__global__ __launch_bounds__(256) void k_prep_zero(
    const float* __restrict__ W0, const float* __restrict__ W1,
    const float* __restrict__ W2, __bf16* __restrict__ W0t_top,
    __bf16* __restrict__ W0t_bot, __bf16* __restrict__ Wt1,
    __bf16* __restrict__ Wt2, int* __restrict__ counts,
    float* __restrict__ sums_all)
{
    const int i = blockIdx.x * 256 + threadIdx.x;
    if (i < NN) counts[i] = 0;
    if (blockIdx.x == 0) {
        for (int j = threadIdx.x; j < 384; j += 256) sums_all[j] = 0.f;
        for (int j = threadIdx.x; j < 4096; j += 256) {
            const int n = j >> 6, k = j & 63;
            W0t_top[n * 64 + k] = (__bf16)W0[k * 64 + n];
            W0t_bot[n * 64 + k] = (__bf16)W0[(64 + k) * 64 + n];
            Wt1[n * 64 + k] = (__bf16)W1[k * 64 + n];
            Wt2[n * 64 + k] = (__bf16)W2[k * 64 + n];
        }
    }
}

// ---------------------------------------------------------------------------
// Fused: dst-degree histogram (blocks 0..3124) + node GEMM (blocks 3125..3906).
// The two are data-independent; fusing overlaps the atomic-bound counting with
// the MFMA-bound node GEMM instead of serializing them on the stream.
// ---------------------------------------------------------------------------
__global__ __launch_bounds__(256) void k_count_node(
    const int* __restrict__ ei, int* __restrict__ counts,
    const float* __restrict__ x, const __bf16* __restrict__ W0t_top,
    const __bf16* __restrict__ W0t_bot, __bf16* __restrict__ P,
    __bf16* __restrict__ Q)
{
    if (blockIdx.x < 3125) {
        const int e = blockIdx.x * 256 + threadIdx.x;
        atomicAdd(&counts[ei[E_EDGES + e]], 1);
        return;
    }

    const int wave = threadIdx.x >> 6;
    const int grp = (blockIdx.x - 3125) * 4 + wave;
    if (grp >= NN / 16) return;  // 3125 groups
    const int lane = threadIdx.x & 63;
    const int quad = lane >> 4, lr = lane & 15;

    bf16x8 aT[4][2], aB[4][2];
#pragma unroll
    for (int mt = 0; mt < 4; ++mt)
#pragma unroll
        for (int s = 0; s < 2; ++s) {
            const int off = (mt * 16 + lr) * 64 + s * 32 + quad * 8;
            aT[mt][s] = *(const bf16x8*)(W0t_top + off);
            aB[mt][s] = *(const bf16x8*)(W0t_bot + off);
        }

    const int node = grp * 16 + lr;
    bf16x8 bx[2];
#pragma unroll
    for (int s = 0; s < 2; ++s) {
        const float4* ap = (const float4*)(x + (size_t)node * 64 + s * 32 + quad * 8);
        const float4 v0 = ap[0], v1 = ap[1];
        bx[s][0] = (__bf16)v0.x; bx[s][1] = (__bf16)v0.y;
        bx[s][2] = (__bf16)v0.z; bx[s][3] = (__bf16)v0.w;
        bx[s][4] = (__bf16)v1.x; bx[s][5] = (__bf16)v1.y;
        bx[s][6] = (__bf16)v1.z; bx[s][7] = (__bf16)v1.w;
    }

    f32x4 accP[4], accQ[4];
#pragma unroll
    for (int mt = 0; mt < 4; ++mt) {
        accP[mt] = (f32x4){0.f, 0.f, 0.f, 0.f};
        accQ[mt] = (f32x4){0.f, 0.f, 0.f, 0.f};
    }
#pragma unroll
    for (int s = 0; s < 2; ++s)
#pragma unroll
        for (int mt = 0; mt < 4; ++mt) {
            accP[mt] = __builtin_amdgcn_mfma_f32_16x16x32_bf16(aT[mt][s], bx[s], accP[mt], 0, 0, 0);
            accQ[mt] = __builtin_amdgcn_mfma_f32_16x16x32_bf16(aB[mt][s], bx[s], accQ[mt], 0, 0, 0);
        }

#pragma unroll
    for (int mt = 0; mt < 4; ++mt) {
        bf16x4 pv, qv;
#pragma unroll
        for (int r = 0; r < 4; ++r) { pv[r] = (__bf16)accP[mt][r]; qv[r] = (__bf16)accQ[mt][r]; }
        const size_t o = (size_t)node * 64 + mt * 16 + quad * 4;
        *(bf16x4*)(P + o) = pv;
        *(bf16x4*)(Q + o) = qv;
    }
}

// ---------------------------------------------------------------------------
// Parallel scan, step A: 196 blocks, per-block sum of 256 counts (coalesced).
// ---------------------------------------------------------------------------
__global__ __launch_bounds__(256) void k_scanA(
    const int* __restrict__ counts, int* __restrict__ bsum)
{
    const int i = blockIdx.x * 256 + threadIdx.x;
    int c = (i < NN) ? counts[i] : 0;
#pragma unroll
    for (int off = 1; off < 64; off <<= 1) c += __shfl_xor(c, off);
    __shared__ int sw[4];
    if ((threadIdx.x & 63) == 0) sw[threadIdx.x >> 6] = c;
    __syncthreads();
    if (threadIdx.x == 0) bsum[blockIdx.x] = sw[0] + sw[1] + sw[2] + sw[3];
}

// ---------------------------------------------------------------------------
// Parallel scan, step B: 196 blocks. Each block scans the 196 block sums in
// LDS (to get its global prefix) + local-scans its own 256 counts, then writes
// offsets/cursor coalesced. Replaces the 1-block serial scan.
// ---------------------------------------------------------------------------
__global__ __launch_bounds__(256) void k_scanB(
    const int* __restrict__ counts, const int* __restrict__ bsum,
    int* __restrict__ offsets, int* __restrict__ cursor)
{
    const int t = threadIdx.x;
    const int b = blockIdx.x;

    __shared__ int sb[256];
    sb[t] = (t < 196) ? bsum[t] : 0;
    __syncthreads();
    for (int off = 1; off < 256; off <<= 1) {
        int v = (t >= off) ? sb[t - off] : 0;
        __syncthreads();
        sb[t] += v;
        __syncthreads();
    }
    const int blockpre = (b == 0) ? 0 : sb[b - 1];

    const int i = b * 256 + t;
    const int c = (i < NN) ? counts[i] : 0;
    __shared__ int sd[256];
    sd[t] = c;
    __syncthreads();
    for (int off = 1; off < 256; off <<= 1) {
        int v = (t >= off) ? sd[t - off] : 0;
        __syncthreads();
        sd[t] += v;
        __syncthreads();
    }
    if (i < NN) {
        const int o = blockpre + sd[t] - c;
        offsets[i] = o;
        cursor[i] = o;
    }
}

// ---------------------------------------------------------------------------
// Fused CSR fill + BN0 stats. 2 threads per edge (32 cols each), grid-stride.
// half0 does the cursor atomic, writes rec2{src,dst} (8B) + eidx (4B); both
// halves gather P[dst]/Q[src] (L2/L3-resident) and accumulate per-column
// sum/sumsq of v = P[dst]+Q[src]. t0 is NEVER materialized.
// ---------------------------------------------------------------------------
__global__ __launch_bounds__(256) void k_fill_stats(
    const int* __restrict__ ei, int* __restrict__ cursor,
    const __bf16* __restrict__ P, const __bf16* __restrict__ Q,
    int2* __restrict__ rec2, int* __restrict__ eidx, float* __restrict__ sums)
{
    float sa[32], sq[32];
#pragma unroll
    for (int j = 0; j < 32; ++j) { sa[j] = 0.f; sq[j] = 0.f; }

    const int lane = threadIdx.x & 63;
    const int stride = gridDim.x * 256;
    for (int s = blockIdx.x * 256 + threadIdx.x; s < 2 * E_EDGES; s += stride) {
        const int e = s >> 1, half = s & 1;
        const int src = ei[e];
        const int dst = ei[E_EDGES + e];
        int pos = 0;
        if (half == 0) pos = atomicAdd(&cursor[dst], 1);
        pos = __shfl(pos, lane & ~1);

        const bf16x8* pp = (const bf16x8*)(P + (size_t)dst * 64 + half * 32);
        const bf16x8* qp = (const bf16x8*)(Q + (size_t)src * 64 + half * 32);
        bf16x8 pf0 = pp[0], pf1 = pp[1], pf2 = pp[2], pf3 = pp[3];
        bf16x8 qf0 = qp[0], qf1 = qp[1], qf2 = qp[2], qf3 = qp[3];

        if (half == 0) {
            rec2[pos] = make_int2(src, dst);
            eidx[pos] = e;
        }

        float v[32];
#pragma unroll
        for (int j = 0; j < 8; ++j) {
            v[j]      = (float)pf0[j] + (float)qf0[j];
            v[8 + j]  = (float)pf1[j] + (float)qf1[j];
            v[16 + j] = (float)pf2[j] + (float)qf2[j];
            v[24 + j] = (float)pf3[j] + (float)qf3[j];
        }
#pragma unroll
        for (int j = 0; j < 32; ++j) { sa[j] += v[j]; sq[j] = fmaf(v[j], v[j], sq[j]); }
    }

#pragma unroll
    for (int off = 2; off < 64; off <<= 1)
#pragma unroll
        for (int j = 0; j < 32; ++j) {
            sa[j] += __shfl_xor(sa[j], off);
            sq[j] += __shfl_xor(sq[j], off);
        }

    __shared__ float red[4][128];
    const int wave = threadIdx.x >> 6;
    if (lane < 2) {
        const int cbase = lane * 32;
#pragma unroll
        for (int j = 0; j < 32; ++j) {
            red[wave][cbase + j] = sa[j];
            red[wave][64 + cbase + j] = sq[j];
        }
    }
    __syncthreads();
    if (threadIdx.x < 128) {
        float v2 = red[0][threadIdx.x] + red[1][threadIdx.x] + red[2][threadIdx.x] + red[3][threadIdx.x];
        atomicAdd(&sums[threadIdx.x], v2);
    }
}

// ---------------------------------------------------------------------------
// Layer-1 GEMM: recomputes t0 rows on the fly via P[dst]+Q[src] gathers
// (dst is CSR-sorted -> P rows cache-hot), applies BN0 affine+relu in fp32,
// MFMA with W1, writes t (bf16, CSR order), fused stats1 epilogue.
// 1250 blocks x 4 waves, 10 groups/wave, rec/gather prefetch pipeline.
// ---------------------------------------------------------------------------
__global__ __launch_bounds__(256) void k_gemm_mid1(
    const __bf16* __restrict__ P, const __bf16* __restrict__ Q,
    const int2* __restrict__ rec2, __bf16* __restrict__ tout,
    const __bf16* __restrict__ Wt, const float* __restrict__ sums_in,
    const float* __restrict__ g, const float* __restrict__ beta,
    float* __restrict__ sums_out)
{
    __shared__ float clds[128];
    __shared__ float sred[4][64], qred[4][64];
    if (threadIdx.x < 64) {
        const float inv_e = 1.f / (float)E_EDGES;
        const float mu = sums_in[threadIdx.x] * inv_e;
        const float var = sums_in[64 + threadIdx.x] * inv_e - mu * mu;
        const float a = g[threadIdx.x] * rsqrtf(var + BN_EPS);
        clds[threadIdx.x] = a;
        clds[64 + threadIdx.x] = beta[threadIdx.x] - mu * a;
    }
    __syncthreads();

    const int wave = threadIdx.x >> 6;
    const int lane = threadIdx.x & 63;
    const int quad = lane >> 4, lr = lane & 15;

    float ar[2][8], cr[2][8];
#pragma unroll
    for (int s = 0; s < 2; ++s)
#pragma unroll
        for (int j = 0; j < 8; ++j) {
            const int k = s * 32 + quad * 8 + j;
            ar[s][j] = clds[k];
            cr[s][j] = clds[64 + k];
        }

    bf16x8 af[4][2];
#pragma unroll
    for (int mt = 0; mt < 4; ++mt)
#pragma unroll
        for (int s = 0; s < 2; ++s)
            af[mt][s] = *(const bf16x8*)(Wt + (mt * 16 + lr) * 64 + s * 32 + quad * 8);

    float ss[16], sq[16];
#pragma unroll
    for (int i = 0; i < 16; ++i) { ss[i] = 0.f; sq[i] = 0.f; }

    const int WAVES = 1250 * 4;
    int grp = blockIdx.x * 4 + wave;      // 10 iterations exactly
    size_t ebase = (size_t)(grp * 16 + lr) * 64;

    // pipeline: rec 2 iterations ahead, gathers 1 iteration ahead
    int2 rc = rec2[grp * 16 + lr];
    bf16x8 pcur0 = *(const bf16x8*)(P + (size_t)rc.y * 64 + quad * 8);
    bf16x8 pcur1 = *(const bf16x8*)(P + (size_t)rc.y * 64 + 32 + quad * 8);
    bf16x8 qcur0 = *(const bf16x8*)(Q + (size_t)rc.x * 64 + quad * 8);
    bf16x8 qcur1 = *(const bf16x8*)(Q + (size_t)rc.x * 64 + 32 + quad * 8);
    int2 rn = rec2[(grp + WAVES) * 16 + lr];

#pragma unroll 1
    for (int it = 0; it < 10; ++it) {
        bf16x8 pn0, pn1, qn0, qn1;
        int2 rn2 = rn;
        if (it < 9) {
            pn0 = *(const bf16x8*)(P + (size_t)rn.y * 64 + quad * 8);
            pn1 = *(const bf16x8*)(P + (size_t)rn.y * 64 + 32 + quad * 8);
            qn0 = *(const bf16x8*)(Q + (size_t)rn.x * 64 + quad * 8);
            qn1 = *(const bf16x8*)(Q + (size_t)rn.x * 64 + 32 + quad * 8);
        }
        if (it < 8) rn2 = rec2[(grp + 2 * WAVES) * 16 + lr];

        bf16x8 bact0, bact1;
#pragma unroll
        for (int j = 0; j < 8; ++j) {
            const float v0 = (float)pcur0[j] + (float)qcur0[j];
            const float v1 = (float)pcur1[j] + (float)qcur1[j];
            bact0[j] = (__bf16)fmaxf(fmaf(v0, ar[0][j], cr[0][j]), 0.f);
            bact1[j] = (__bf16)fmaxf(fmaf(v1, ar[1][j], cr[1][j]), 0.f);
        }

        f32x4 acc[4];
#pragma unroll
        for (int mt = 0; mt < 4; ++mt) acc[mt] = (f32x4){0.f, 0.f, 0.f, 0.f};
#pragma unroll
        for (int mt = 0; mt < 4; ++mt) {
            acc[mt] = __builtin_amdgcn_mfma_f32_16x16x32_bf16(af[mt][0], bact0, acc[mt], 0, 0, 0);
            acc[mt] = __builtin_amdgcn_mfma_f32_16x16x32_bf16(af[mt][1], bact1, acc[mt], 0, 0, 0);
        }

#pragma unroll
        for (int mt = 0; mt < 4; ++mt) {
            bf16x4 pv;
#pragma unroll
            for (int r = 0; r < 4; ++r) pv[r] = (__bf16)acc[mt][r];
            *(bf16x4*)(tout + ebase + mt * 16 + quad * 4) = pv;
#pragma unroll
            for (int r = 0; r < 4; ++r) {
                const float v = acc[mt][r];
                ss[mt * 4 + r] += v;
                sq[mt * 4 + r] = fmaf(v, v, sq[mt * 4 + r]);
            }
        }

        pcur0 = pn0; pcur1 = pn1; qcur0 = qn0; qcur1 = qn1;
        rn = rn2;
        grp += WAVES;
        ebase = (size_t)(grp * 16 + lr) * 64;
    }

#pragma unroll
    for (int i = 0; i < 16; ++i) {
        ss[i] += __shfl_xor(ss[i], 1); ss[i] += __shfl_xor(ss[i], 2);
        ss[i] += __shfl_xor(ss[i], 4); ss[i] += __shfl_xor(ss[i], 8);
        sq[i] += __shfl_xor(sq[i], 1); sq[i] += __shfl_xor(sq[i], 2);
        sq[i] += __shfl_xor(sq[i], 4); sq[i] += __shfl_xor(sq[i], 8);
    }
    if (lr == 0) {
#pragma unroll
        for (int mt = 0; mt < 4; ++mt)
#pragma unroll
            for (int r = 0; r < 4; ++r) {
                sred[wave][mt * 16 + quad * 4 + r] = ss[mt * 4 + r];
                qred[wave][mt * 16 + quad * 4 + r] = sq[mt * 4 + r];
            }
    }
    __syncthreads();
    if (threadIdx.x < 64) {
        const int c = threadIdx.x;
        atomicAdd(&sums_out[c], sred[0][c] + sred[1][c] + sred[2][c] + sred[3][c]);
        atomicAdd(&sums_out[64 + c], qred[0][c] + qred[1][c] + qred[2][c] + qred[3][c]);
    }
}

// ---------------------------------------------------------------------------
// Layer-2 GEMM (streaming): bf16 in -> bf16 out in place; prev-BN
// affine+relu on load; fused stats epilogue. 1250 blocks x 4 waves.
// ---------------------------------------------------------------------------
__global__ __launch_bounds__(256) void k_gemm_mid(
    const __bf16* __restrict__ tin, __bf16* __restrict__ tout,
    const __bf16* __restrict__ Wt, const float* __restrict__ sums_in,
    const float* __restrict__ g, const float* __restrict__ beta,
    float* __restrict__ sums_out)
{
    __shared__ float clds[128];
    __shared__ float sred[4][64], qred[4][64];
    if (threadIdx.x < 64) {
        const float inv_e = 1.f / (float)E_EDGES;
        const float mu = sums_in[threadIdx.x] * inv_e;
        const float var = sums_in[64 + threadIdx.x] * inv_e - mu * mu;
        const float a = g[threadIdx.x] * rsqrtf(var + BN_EPS);
        clds[threadIdx.x] = a;
        clds[64 + threadIdx.x] = beta[threadIdx.x] - mu * a;
    }
    __syncthreads();

    const int wave = threadIdx.x >> 6;
    const int lane = threadIdx.x & 63;
    const int quad = lane >> 4, lr = lane & 15;

    float ar[2][8], cr[2][8];
#pragma unroll
    for (int s = 0; s < 2; ++s)
#pragma unroll
        for (int j = 0; j < 8; ++j) {
            const int k = s * 32 + quad * 8 + j;
            ar[s][j] = clds[k];
            cr[s][j] = clds[64 + k];
        }

    bf16x8 af[4][2];
#pragma unroll
    for (int mt = 0; mt < 4; ++mt)
#pragma unroll
        for (int s = 0; s < 2; ++s)
            af[mt][s] = *(const bf16x8*)(Wt + (mt * 16 + lr) * 64 + s * 32 + quad * 8);

    float ss[16], sq[16];
#pragma unroll
    for (int i = 0; i < 16; ++i) { ss[i] = 0.f; sq[i] = 0.f; }

    const int WAVES = 1250 * 4;
    int grp = blockIdx.x * 4 + wave;      // 10 iterations exactly
    size_t ebase = (size_t)(grp * 16 + lr) * 64;

    bf16x8 bcur0 = *(const bf16x8*)(tin + ebase + quad * 8);
    bf16x8 bcur1 = *(const bf16x8*)(tin + ebase + 32 + quad * 8);

#pragma unroll 1
    for (int it = 0; it < 10; ++it) {
        const int gn = grp + WAVES;
        const size_t enext = (size_t)(gn * 16 + lr) * 64;
        bf16x8 bn0, bn1;
        if (it < 9) {
            bn0 = *(const bf16x8*)(tin + enext + quad * 8);
            bn1 = *(const bf16x8*)(tin + enext + 32 + quad * 8);
        }

        bf16x8 bact0, bact1;
#pragma unroll
        for (int j = 0; j < 8; ++j) {
            bact0[j] = (__bf16)fmaxf(fmaf((float)bcur0[j], ar[0][j], cr[0][j]), 0.f);
            bact1[j] = (__bf16)fmaxf(fmaf((float)bcur1[j], ar[1][j], cr[1][j]), 0.f);
        }

        f32x4 acc[4];
#pragma unroll
        for (int mt = 0; mt < 4; ++mt) acc[mt] = (f32x4){0.f, 0.f, 0.f, 0.f};
#pragma unroll
        for (int mt = 0; mt < 4; ++mt) {
            acc[mt] = __builtin_amdgcn_mfma_f32_16x16x32_bf16(af[mt][0], bact0, acc[mt], 0, 0, 0);
            acc[mt] = __builtin_amdgcn_mfma_f32_16x16x32_bf16(af[mt][1], bact1, acc[mt], 0, 0, 0);
        }

#pragma unroll
        for (int mt = 0; mt < 4; ++mt) {
            bf16x4 pv;
#pragma unroll
            for (int r = 0; r < 4; ++r) pv[r] = (__bf16)acc[mt][r];
            *(bf16x4*)(tout + ebase + mt * 16 + quad * 4) = pv;
#pragma unroll
            for (int r = 0; r < 4; ++r) {
                const float v = acc[mt][r];
                ss[mt * 4 + r] += v;
                sq[mt * 4 + r] = fmaf(v, v, sq[mt * 4 + r]);
            }
        }

        bcur0 = bn0; bcur1 = bn1;
        grp = gn; ebase = enext;
    }

#pragma unroll
    for (int i = 0; i < 16; ++i) {
        ss[i] += __shfl_xor(ss[i], 1); ss[i] += __shfl_xor(ss[i], 2);
        ss[i] += __shfl_xor(ss[i], 4); ss[i] += __shfl_xor(ss[i], 8);
        sq[i] += __shfl_xor(sq[i], 1); sq[i] += __shfl_xor(sq[i], 2);
        sq[i] += __shfl_xor(sq[i], 4); sq[i] += __shfl_xor(sq[i], 8);
    }
    if (lr == 0) {
#pragma unroll
        for (int mt = 0; mt < 4; ++mt)
#pragma unroll
            for (int r = 0; r < 4; ++r) {
                sred[wave][mt * 16 + quad * 4 + r] = ss[mt * 4 + r];
                qred[wave][mt * 16 + quad * 4 + r] = sq[mt * 4 + r];
            }
    }
    __syncthreads();
    if (threadIdx.x < 64) {
        const int c = threadIdx.x;
        atomicAdd(&sums_out[c], sred[0][c] + sred[1][c] + sred[2][c] + sred[3][c]);
        atomicAdd(&sums_out[64 + c], qred[0][c] + qred[1][c] + qred[2][c] + qred[3][c]);
    }
}

// ---------------------------------------------------------------------------
// Final: per node (one wave), node's rows are CONTIGUOUS in tb (CSR order).
// 8 rows x 8 lanes per step: lane reads 16B bf16 (coalesced 1KB/wave),
// applies BN2+relu, scatter-writes the fp32 edge_activations row to its
// original edge slot (full-line writes), reduces, writes mean.
// ---------------------------------------------------------------------------
__global__ __launch_bounds__(256) void k_gather_apply(
    const __bf16* __restrict__ tb, const int* __restrict__ offsets,
    const int* __restrict__ counts, const int* __restrict__ eidx,
    const float* __restrict__ sums_in, const float* __restrict__ g,
    const float* __restrict__ beta, float* __restrict__ tea,
    float* __restrict__ out)
{
    __shared__ float clds[128];
    if (threadIdx.x < 64) {
        const float inv_e = 1.f / (float)E_EDGES;
        const float mu = sums_in[threadIdx.x] * inv_e;
        const float var = sums_in[64 + threadIdx.x] * inv_e - mu * mu;
        const float a = g[threadIdx.x] * rsqrtf(var + BN_EPS);
        clds[threadIdx.x] = a;
        clds[64 + threadIdx.x] = beta[threadIdx.x] - mu * a;
    }
    __syncthreads();

    const int node = blockIdx.x * 4 + (threadIdx.x >> 6);
    const int lane = threadIdx.x & 63;
    const int es = lane >> 3;  // row slot 0..7
    const int cc = lane & 7;   // col chunk (8 cols)

    float a[8], c[8];
#pragma unroll
    for (int j = 0; j < 8; ++j) { a[j] = clds[cc * 8 + j]; c[j] = clds[64 + cc * 8 + j]; }

    const int beg = offsets[node];
    const int cnt = counts[node];

    float acc8[8];
#pragma unroll
    for (int j = 0; j < 8; ++j) acc8[j] = 0.f;

    for (int i = 0; i < cnt; i += 8) {
        const int sub = i + es;
        if (sub < cnt) {
            const int p = beg + sub;
            const bf16x8 v = *(const bf16x8*)(tb + (size_t)p * 64 + cc * 8);
            const int e = eidx[p];
            float vv[8];
#pragma unroll
            for (int j = 0; j < 8; ++j)
                vv[j] = fmaxf(fmaf((float)v[j], a[j], c[j]), 0.f);
            float* rp = tea + (size_t)e * 64 + cc * 8;
            *(float4*)rp = make_float4(vv[0], vv[1], vv[2], vv[3]);
            *(float4*)(rp + 4) = make_float4(vv[4], vv[5], vv[6], vv[7]);
#pragma unroll
            for (int j = 0; j < 8; ++j) acc8[j] += vv[j];
        }
    }

#pragma unroll
    for (int j = 0; j < 8; ++j) {
        acc8[j] += __shfl_xor(acc8[j], 8);
        acc8[j] += __shfl_xor(acc8[j], 16);
        acc8[j] += __shfl_xor(acc8[j], 32);
    }
    if (lane < 8) {  // es==0, cc==lane
        const float inv = 1.f / fmaxf((float)cnt, 1.f);
        float* op = out + (size_t)node * 64 + lane * 8;
        *(float4*)op = make_float4(acc8[0] * inv, acc8[1] * inv, acc8[2] * inv, acc8[3] * inv);
        *(float4*)(op + 4) = make_float4(acc8[4] * inv, acc8[5] * inv, acc8[6] * inv, acc8[7] * inv);
    }
}

extern "C" void kernel_launch(void* const* d_in, const int* in_sizes, int n_in,
                              void* d_out, int out_size, void* d_ws, size_t ws_size,
                              hipStream_t stream)
{
    (void)in_sizes; (void)n_in; (void)out_size; (void)ws_size;

    const float* x     = (const float*)d_in[0];
    const int*   ei    = (const int*)d_in[1];
    const float* W0    = (const float*)d_in[2];
    const float* g0    = (const float*)d_in[4];
    const float* beta0 = (const float*)d_in[5];
    const float* W1    = (const float*)d_in[6];
    const float* g1    = (const float*)d_in[8];
    const float* beta1 = (const float*)d_in[9];
    const float* W2    = (const float*)d_in[10];
    const float* g2    = (const float*)d_in[12];
    const float* beta2 = (const float*)d_in[13];

    float* out = (float*)d_out;            // [NN*64] node output
    float* tea = out + (size_t)NN * 64;    // [E*64] fp32 edge_activations

    char* ws = (char*)d_ws;
    int*    counts  = (int*)(ws + 0);             // 200000 B
    int*    offsets = (int*)(ws + 200704);
    int*    cursor  = (int*)(ws + 401408);
    float*  sums0   = (float*)(ws + 602112);      // 512 B each, contiguous
    float*  sums1   = (float*)(ws + 602624);
    float*  sums2   = (float*)(ws + 603136);
    int*    bsum    = (int*)(ws + 603648);        // 784 B (196 ints)
    __bf16* W0t_top = (__bf16*)(ws + 604672);     // 8192 B each
    __bf16* W0t_bot = (__bf16*)(ws + 612864);
    __bf16* Wt1     = (__bf16*)(ws + 621056);
    __bf16* Wt2     = (__bf16*)(ws + 629248);
    __bf16* P       = (__bf16*)(ws + 637440);     // 6.4 MB
    __bf16* Q       = (__bf16*)(ws + 7037440);    // 6.4 MB
    int2*   rec2    = (int2*)(ws + 13437440);     // 6.4 MB {src,dst}
    int*    eidx    = (int*)(ws + 19837440);      // 3.2 MB original edge id
    __bf16* tb      = (__bf16*)(ws + 23037440);   // 102.4 MB bf16 t (CSR order)

    // 1: zero counts/sums + weight prep (196 blocks)
    k_prep_zero<<<196, 256, 0, stream>>>(W0, W1, W2, W0t_top, W0t_bot, Wt1, Wt2,
                                         counts, sums0);
    // 2: fused degree-count + node GEMM (independent work, one dispatch)
    k_count_node<<<3907, 256, 0, stream>>>(ei, counts, x, W0t_top, W0t_bot, P, Q);
    // 3+4: parallel scan (replaces 1-block serial scan)
    k_scanA<<<196, 256, 0, stream>>>(counts, bsum);
    k_scanB<<<196, 256, 0, stream>>>(counts, bsum, offsets, cursor);
    // 5: fused CSR fill + BN0 stats (t0 never materialized)
    k_fill_stats<<<1563, 256, 0, stream>>>(ei, cursor, P, Q, rec2, eidx, sums0);
    // 6: layer1 (gather P[dst]+Q[src] on the fly); 7: layer2 streaming in place
    k_gemm_mid1<<<1250, 256, 0, stream>>>(P, Q, rec2, tb, Wt1, sums0, g0, beta0, sums1);
    k_gemm_mid<<<1250, 256, 0, stream>>>(tb, tb, Wt2, sums1, g1, beta1, sums2);
    // 8: BN2 + relu + scatter to tea + per-node mean
    k_gather_apply<<<NN / 4, 256, 0, stream>>>(tb, offsets, counts, eidx,
                                               sums2, g2, beta2, tea, out);
}